// Round 2
// baseline (2110.485 us; speedup 1.0000x reference)
//
#include <hip/hip_runtime.h>
#include <hip/hip_bf16.h>
#include <math.h>

// GraphSAGE 3-layer, mean aggr, fp32.
// CSR scatter replaced by dst-bucketing (128 nodes/bucket):
//   B1 count buckets -> B2 scan -> B3 bin (src|dstLocal packed, grouped writes)
//   -> agg processes one bucket/block with LDS accumulators (no col/deg arrays).
// Layers 1-2: agg(64) -> lin(relu). Layer 3: pre-transform to 40 dims, agg(40)
// accumulated onto self-path staged in d_out, log_softmax in place.

#define BK_SHIFT 7
#define BK_NODES 128
#define NB_MAX   1024

// ---------------- bucket count ----------------
__global__ __launch_bounds__(256) void bcount_kernel(const int* __restrict__ dstA,
                                                     int* __restrict__ bcount, int E, int NB) {
    __shared__ int lc[NB_MAX];
    int t = threadIdx.x;
    for (int i = t; i < NB; i += 256) lc[i] = 0;
    __syncthreads();
    int step = gridDim.x * 256;
    for (int e = blockIdx.x * 256 + t; e < E; e += step)
        atomicAdd(&lc[dstA[e] >> BK_SHIFT], 1);
    __syncthreads();
    for (int i = t; i < NB; i += 256)
        if (lc[i]) atomicAdd(&bcount[i], lc[i]);
}

// ---------------- scan bucket counts (single block, NB <= 1024) ----------------
__global__ __launch_bounds__(1024) void bscan_kernel(const int* __restrict__ bcount,
                                                     int* __restrict__ bbase,
                                                     int* __restrict__ cursor, int NB, int E) {
    __shared__ int s[1024];
    int t = threadIdx.x;
    int v = (t < NB) ? bcount[t] : 0;
    s[t] = v;
    __syncthreads();
    for (int off = 1; off < 1024; off <<= 1) {
        int x = 0;
        if (t >= off) x = s[t - off];
        __syncthreads();
        s[t] += x;
        __syncthreads();
    }
    if (t < NB) {
        int ex = s[t] - v;
        bbase[t] = ex;
        cursor[t] = ex;
    }
    if (t == 0) bbase[NB] = E;
}

// ---------------- bin edges into buckets ----------------
__global__ __launch_bounds__(256) void bin_kernel(const int* __restrict__ srcA,
                                                  const int* __restrict__ dstA,
                                                  int* __restrict__ cursor,
                                                  int* __restrict__ binned, int E, int NB) {
    __shared__ int lc[NB_MAX];
    __shared__ int lbase[NB_MAX];
    int t = threadIdx.x;
    int chunk = (E + gridDim.x - 1) / gridDim.x;
    int e0 = blockIdx.x * chunk;
    int e1 = min(E, e0 + chunk);
    for (int i = t; i < NB; i += 256) lc[i] = 0;
    __syncthreads();
    for (int e = e0 + t; e < e1; e += 256)
        atomicAdd(&lc[dstA[e] >> BK_SHIFT], 1);
    __syncthreads();
    for (int i = t; i < NB; i += 256) {
        int c = lc[i];
        lbase[i] = c ? atomicAdd(&cursor[i], c) : 0;
    }
    __syncthreads();
    for (int i = t; i < NB; i += 256) lc[i] = 0;
    __syncthreads();
    for (int e = e0 + t; e < e1; e += 256) {
        int d = dstA[e];
        int b = d >> BK_SHIFT;
        int r = atomicAdd(&lc[b], 1);
        binned[lbase[b] + r] = srcA[e] | ((d & (BK_NODES - 1)) << 24);
    }
}

// ---------------- bucketed mean aggregation ----------------
// One bucket (128 dst nodes) per block. 16-lane group per edge gathers x[src]
// (FV float4s live) and accumulates into padded LDS acc. Mean + optional
// self-path add (L3) on write-out.

template<int FV, int LDX, bool L3>
__global__ __launch_bounds__(256) void agg_bucket_kernel(const float* __restrict__ X,
                                                         const int* __restrict__ bbase,
                                                         const int* __restrict__ binned,
                                                         float* __restrict__ OUT, int n) {
    __shared__ float acc[BK_NODES][FV * 4 + 1];
    __shared__ int dcount[BK_NODES];
    int t = threadIdx.x;
    float* accf = (float*)acc;
    for (int i = t; i < BK_NODES * (FV * 4 + 1); i += 256) accf[i] = 0.f;
    for (int i = t; i < BK_NODES; i += 256) dcount[i] = 0;
    __syncthreads();

    int b = blockIdx.x;
    int e0 = bbase[b], e1 = bbase[b + 1];
    int g = t >> 4, lane = t & 15;
    bool act = lane < FV;
    int e = e0 + g;
    for (; e + 16 < e1; e += 32) {
        unsigned p0 = (unsigned)binned[e];
        unsigned p1 = (unsigned)binned[e + 16];
        int s0 = p0 & 0xFFFFFF, d0 = p0 >> 24;
        int s1 = p1 & 0xFFFFFF, d1 = p1 >> 24;
        if (act) {
            float4 v0 = *(const float4*)(X + (size_t)s0 * LDX + lane * 4);
            float4 v1 = *(const float4*)(X + (size_t)s1 * LDX + lane * 4);
            atomicAdd(&acc[d0][lane * 4 + 0], v0.x);
            atomicAdd(&acc[d0][lane * 4 + 1], v0.y);
            atomicAdd(&acc[d0][lane * 4 + 2], v0.z);
            atomicAdd(&acc[d0][lane * 4 + 3], v0.w);
            atomicAdd(&acc[d1][lane * 4 + 0], v1.x);
            atomicAdd(&acc[d1][lane * 4 + 1], v1.y);
            atomicAdd(&acc[d1][lane * 4 + 2], v1.z);
            atomicAdd(&acc[d1][lane * 4 + 3], v1.w);
        }
        if (lane == 0) {
            atomicAdd(&dcount[d0], 1);
            atomicAdd(&dcount[d1], 1);
        }
    }
    if (e < e1) {
        unsigned p0 = (unsigned)binned[e];
        int s0 = p0 & 0xFFFFFF, d0 = p0 >> 24;
        if (act) {
            float4 v0 = *(const float4*)(X + (size_t)s0 * LDX + lane * 4);
            atomicAdd(&acc[d0][lane * 4 + 0], v0.x);
            atomicAdd(&acc[d0][lane * 4 + 1], v0.y);
            atomicAdd(&acc[d0][lane * 4 + 2], v0.z);
            atomicAdd(&acc[d0][lane * 4 + 3], v0.w);
        }
        if (lane == 0) atomicAdd(&dcount[d0], 1);
    }
    __syncthreads();

    int nodebase = b * BK_NODES;
    for (int i = t; i < BK_NODES * FV; i += 256) {
        int r = i / FV, q = i % FV;
        int node = nodebase + r;
        if (node >= n) continue;
        int dc = dcount[r];
        float inv = 1.f / (float)(dc > 0 ? dc : 1);
        float4 o;
        o.x = acc[r][q * 4 + 0] * inv;
        o.y = acc[r][q * 4 + 1] * inv;
        o.z = acc[r][q * 4 + 2] * inv;
        o.w = acc[r][q * 4 + 3] * inv;
        float* op = OUT + (size_t)node * LDX + q * 4;
        if (L3) {
            float4 sv = *(const float4*)op;
            o.x += sv.x; o.y += sv.y; o.z += sv.z; o.w += sv.w;
        }
        *(float4*)op = o;
    }
}

// ---------------- fused linear: OUT = relu(A@Wl^T + b + X@Wr^T) ----------------
// 32 rows/block; thread = (rowpair, colgroup of 4). In-place X==OUT is safe:
// block stages its own rows before writing them.

__global__ __launch_bounds__(256) void lin12_kernel(const float* __restrict__ X,
                                                    const float* __restrict__ A,
                                                    const float* __restrict__ Wl,
                                                    const float* __restrict__ Wr,
                                                    const float* __restrict__ bias,
                                                    float* __restrict__ OUT) {
    __shared__ float Wls[64][65];
    __shared__ float Wrs[64][65];
    __shared__ float Xs[32][65];
    __shared__ float As[32][65];
    int t = threadIdx.x;
    int rowbase = blockIdx.x * 32;
#pragma unroll
    for (int it = 0; it < 4; ++it) {
        int idx4 = it * 256 + t;          // 1024 float4 = 64x64
        int c = idx4 >> 4, kq = (idx4 & 15) * 4;
        float4 wl = ((const float4*)Wl)[idx4];
        float4 wr = ((const float4*)Wr)[idx4];
        Wls[c][kq] = wl.x; Wls[c][kq + 1] = wl.y; Wls[c][kq + 2] = wl.z; Wls[c][kq + 3] = wl.w;
        Wrs[c][kq] = wr.x; Wrs[c][kq + 1] = wr.y; Wrs[c][kq + 2] = wr.z; Wrs[c][kq + 3] = wr.w;
    }
#pragma unroll
    for (int it = 0; it < 2; ++it) {
        int idx4 = it * 256 + t;          // 512 float4 = 32 rows x 16
        int r = idx4 >> 4, kq = (idx4 & 15) * 4;
        float4 xv = ((const float4*)(X + (size_t)(rowbase + r) * 64))[idx4 & 15];
        float4 av = ((const float4*)(A + (size_t)(rowbase + r) * 64))[idx4 & 15];
        Xs[r][kq] = xv.x; Xs[r][kq + 1] = xv.y; Xs[r][kq + 2] = xv.z; Xs[r][kq + 3] = xv.w;
        As[r][kq] = av.x; As[r][kq + 1] = av.y; As[r][kq + 2] = av.z; As[r][kq + 3] = av.w;
    }
    __syncthreads();
    int rp = t >> 4, cg = t & 15;
    int r0 = rp * 2, r1 = r0 + 1, c0 = cg * 4;
    float4 acc0 = {0, 0, 0, 0}, acc1 = {0, 0, 0, 0};
#pragma unroll
    for (int k = 0; k < 64; ++k) {
        float a0 = As[r0][k], a1 = As[r1][k];
        float x0 = Xs[r0][k], x1 = Xs[r1][k];
        float wl0 = Wls[c0][k], wl1 = Wls[c0 + 1][k], wl2 = Wls[c0 + 2][k], wl3 = Wls[c0 + 3][k];
        float wr0 = Wrs[c0][k], wr1 = Wrs[c0 + 1][k], wr2 = Wrs[c0 + 2][k], wr3 = Wrs[c0 + 3][k];
        acc0.x = fmaf(a0, wl0, fmaf(x0, wr0, acc0.x));
        acc0.y = fmaf(a0, wl1, fmaf(x0, wr1, acc0.y));
        acc0.z = fmaf(a0, wl2, fmaf(x0, wr2, acc0.z));
        acc0.w = fmaf(a0, wl3, fmaf(x0, wr3, acc0.w));
        acc1.x = fmaf(a1, wl0, fmaf(x1, wr0, acc1.x));
        acc1.y = fmaf(a1, wl1, fmaf(x1, wr1, acc1.y));
        acc1.z = fmaf(a1, wl2, fmaf(x1, wr2, acc1.z));
        acc1.w = fmaf(a1, wl3, fmaf(x1, wr3, acc1.w));
    }
    float4 bb = ((const float4*)bias)[cg];
    acc0.x = fmaxf(acc0.x + bb.x, 0.f); acc0.y = fmaxf(acc0.y + bb.y, 0.f);
    acc0.z = fmaxf(acc0.z + bb.z, 0.f); acc0.w = fmaxf(acc0.w + bb.w, 0.f);
    acc1.x = fmaxf(acc1.x + bb.x, 0.f); acc1.y = fmaxf(acc1.y + bb.y, 0.f);
    acc1.z = fmaxf(acc1.z + bb.z, 0.f); acc1.w = fmaxf(acc1.w + bb.w, 0.f);
    ((float4*)(OUT + (size_t)(rowbase + r0) * 64))[cg] = acc0;
    ((float4*)(OUT + (size_t)(rowbase + r1) * 64))[cg] = acc1;
}

// ---------------- layer-3 pre-transform: Z = X@Wl3^T (N,40), R = X@Wr3^T + b3 ----------------

__global__ __launch_bounds__(256) void lin3_kernel(const float* __restrict__ X,
                                                   const float* __restrict__ Wl,
                                                   const float* __restrict__ Wr,
                                                   const float* __restrict__ bias,
                                                   float* __restrict__ Z,
                                                   float* __restrict__ R) {
    __shared__ float Ws[80][65];
    __shared__ float Xs[20][65];
    int t = threadIdx.x;
    int rowbase = blockIdx.x * 20;
#pragma unroll
    for (int it = 0; it < 5; ++it) {
        int idx4 = it * 256 + t;          // 1280 float4 = 80x64
        int c = idx4 >> 4, kq = (idx4 & 15) * 4;
        float4 w = (c < 40) ? ((const float4*)Wl)[idx4] : ((const float4*)Wr)[idx4 - 640];
        Ws[c][kq] = w.x; Ws[c][kq + 1] = w.y; Ws[c][kq + 2] = w.z; Ws[c][kq + 3] = w.w;
    }
#pragma unroll
    for (int it = 0; it < 2; ++it) {
        int idx4 = it * 256 + t;          // 320 float4 = 20 rows x 16
        if (idx4 < 320) {
            int r = idx4 >> 4, kq = (idx4 & 15) * 4;
            float4 xv = ((const float4*)(X + (size_t)(rowbase + r) * 64))[idx4 & 15];
            Xs[r][kq] = xv.x; Xs[r][kq + 1] = xv.y; Xs[r][kq + 2] = xv.z; Xs[r][kq + 3] = xv.w;
        }
    }
    __syncthreads();
    if (t >= 200) return;
    int rp = t / 20, cg = t % 20;
    int r0 = rp * 2, r1 = r0 + 1;
    bool lpath = cg < 10;
    int c0 = (lpath ? cg : cg - 10) * 4;
    int wc = lpath ? c0 : 40 + c0;
    float4 acc0 = {0, 0, 0, 0}, acc1 = {0, 0, 0, 0};
#pragma unroll
    for (int k = 0; k < 64; ++k) {
        float x0 = Xs[r0][k], x1 = Xs[r1][k];
        float w0 = Ws[wc][k], w1 = Ws[wc + 1][k], w2 = Ws[wc + 2][k], w3 = Ws[wc + 3][k];
        acc0.x = fmaf(x0, w0, acc0.x); acc0.y = fmaf(x0, w1, acc0.y);
        acc0.z = fmaf(x0, w2, acc0.z); acc0.w = fmaf(x0, w3, acc0.w);
        acc1.x = fmaf(x1, w0, acc1.x); acc1.y = fmaf(x1, w1, acc1.y);
        acc1.z = fmaf(x1, w2, acc1.z); acc1.w = fmaf(x1, w3, acc1.w);
    }
    if (!lpath) {
        float4 bb = ((const float4*)bias)[c0 >> 2];
        acc0.x += bb.x; acc0.y += bb.y; acc0.z += bb.z; acc0.w += bb.w;
        acc1.x += bb.x; acc1.y += bb.y; acc1.z += bb.z; acc1.w += bb.w;
    }
    float* dp = lpath ? Z : R;
    ((float4*)(dp + (size_t)(rowbase + r0) * 40))[c0 >> 2] = acc0;
    ((float4*)(dp + (size_t)(rowbase + r1) * 40))[c0 >> 2] = acc1;
}

// ---------------- log_softmax in place, one wave per node ----------------

__global__ __launch_bounds__(256) void lsm_kernel(float* __restrict__ out, int n) {
    int t = threadIdx.x;
    int node = blockIdx.x * 4 + (t >> 6);
    if (node >= n) return;
    int lane = t & 63;
    float v = (lane < 40) ? out[(size_t)node * 40 + lane] : -3.4e38f;
    float m = v;
#pragma unroll
    for (int off = 32; off > 0; off >>= 1) m = fmaxf(m, __shfl_xor(m, off));
    float e = (lane < 40) ? expf(v - m) : 0.f;
    float ssum = e;
#pragma unroll
    for (int off = 32; off > 0; off >>= 1) ssum += __shfl_xor(ssum, off);
    if (lane < 40) out[(size_t)node * 40 + lane] = v - m - logf(ssum);
}

// ---------------- launch ----------------

extern "C" void kernel_launch(void* const* d_in, const int* in_sizes, int n_in,
                              void* d_out, int out_size, void* d_ws, size_t ws_size,
                              hipStream_t stream) {
    const float* x   = (const float*)d_in[0];
    const int*   ei  = (const int*)d_in[1];
    const float* Wl1 = (const float*)d_in[2];
    const float* Wr1 = (const float*)d_in[3];
    const float* b1  = (const float*)d_in[4];
    const float* Wl2 = (const float*)d_in[5];
    const float* Wr2 = (const float*)d_in[6];
    const float* b2  = (const float*)d_in[7];
    const float* Wl3 = (const float*)d_in[8];
    const float* Wr3 = (const float*)d_in[9];
    const float* b3  = (const float*)d_in[10];
    float* out = (float*)d_out;

    const int N = in_sizes[0] / 64;
    const int E = in_sizes[1] / 2;
    const int NB = (N + BK_NODES - 1) / BK_NODES;   // 782 for N=100000
    const int* srcA = ei;
    const int* dstA = ei + E;

    char* ws = (char*)d_ws;
    size_t off = 0;
    auto alloc = [&](size_t bytes) {
        off = (off + 255) & ~(size_t)255;
        char* p = ws + off;
        off += bytes;
        return p;
    };
    int*   bcount = (int*)alloc((size_t)(NB_MAX + 1) * 4);
    int*   bbase  = (int*)alloc((size_t)(NB_MAX + 1) * 4);
    int*   cursor = (int*)alloc((size_t)NB_MAX * 4);
    int*   binned = (int*)alloc((size_t)E * 4);
    float* AGG    = (float*)alloc((size_t)N * 64 * 4);
    float* Hb     = (float*)alloc((size_t)N * 64 * 4);

    // bucket build
    hipMemsetAsync(bcount, 0, (size_t)(NB + 1) * 4, stream);
    bcount_kernel<<<256, 256, 0, stream>>>(dstA, bcount, E, NB);
    bscan_kernel<<<1, 1024, 0, stream>>>(bcount, bbase, cursor, NB, E);
    bin_kernel<<<128, 256, 0, stream>>>(srcA, dstA, cursor, binned, E, NB);

    // layer 1: h1 = relu(mean(x)@Wl1^T + b1 + x@Wr1^T)
    agg_bucket_kernel<16, 64, false><<<NB, 256, 0, stream>>>(x, bbase, binned, AGG, N);
    lin12_kernel<<<N / 32, 256, 0, stream>>>(x, AGG, Wl1, Wr1, b1, Hb);

    // layer 2 (in-place on Hb)
    agg_bucket_kernel<16, 64, false><<<NB, 256, 0, stream>>>(Hb, bbase, binned, AGG, N);
    lin12_kernel<<<N / 32, 256, 0, stream>>>(Hb, AGG, Wl2, Wr2, b2, Hb);

    // layer 3: pre-transform (agg is linear): Z = h2@Wl3^T (N,40) in AGG, R = h2@Wr3^T+b3 in d_out
    lin3_kernel<<<N / 20, 256, 0, stream>>>(Hb, Wl3, Wr3, b3, AGG, out);
    agg_bucket_kernel<10, 40, true><<<NB, 256, 0, stream>>>(AGG, bbase, binned, out, N);

    // log_softmax in place
    lsm_kernel<<<(N + 3) / 4, 256, 0, stream>>>(out, N);
}

// Round 3
// 519.461 us; speedup vs baseline: 4.0628x; 4.0628x over previous
//
#include <hip/hip_runtime.h>
#include <hip/hip_bf16.h>
#include <math.h>

// GraphSAGE 3-layer, mean aggr, fp32.
// Build: dst-bucket (128 nodes/bucket) count -> scan -> bin (semi-coalesced)
//        -> per-bucket LDS counting sort => sorted CSR (row_start, col).
// Agg:   per-node 16-lane gather from CSR (round-1 structure, unroll x4).
// Layers 1-2: agg(64) -> fused lin(relu). Layer 3: pre-transform to 40 dims,
// agg(40) added onto self-path staged in d_out, log_softmax in place.

#define BK_SHIFT 7
#define BK_NODES 128
#define NB_MAX   1024

// ---------------- bucket count ----------------
__global__ __launch_bounds__(256) void bcount_kernel(const int* __restrict__ dstA,
                                                     int* __restrict__ bcount, int E, int NB) {
    __shared__ int lc[NB_MAX];
    int t = threadIdx.x;
    for (int i = t; i < NB; i += 256) lc[i] = 0;
    __syncthreads();
    int step = gridDim.x * 256;
    for (int e = blockIdx.x * 256 + t; e < E; e += step)
        atomicAdd(&lc[dstA[e] >> BK_SHIFT], 1);
    __syncthreads();
    for (int i = t; i < NB; i += 256)
        if (lc[i]) atomicAdd(&bcount[i], lc[i]);
}

// ---------------- scan bucket counts (single block, NB <= 1024) ----------------
__global__ __launch_bounds__(1024) void bscan_kernel(const int* __restrict__ bcount,
                                                     int* __restrict__ bbase,
                                                     int* __restrict__ cursor, int NB, int E) {
    __shared__ int s[1024];
    int t = threadIdx.x;
    int v = (t < NB) ? bcount[t] : 0;
    s[t] = v;
    __syncthreads();
    for (int off = 1; off < 1024; off <<= 1) {
        int x = 0;
        if (t >= off) x = s[t - off];
        __syncthreads();
        s[t] += x;
        __syncthreads();
    }
    if (t < NB) {
        int ex = s[t] - v;
        bbase[t] = ex;
        cursor[t] = ex;
    }
    if (t == 0) bbase[NB] = E;
}

// ---------------- bin edges into buckets (src | dstLocal<<24) ----------------
__global__ __launch_bounds__(256) void bin_kernel(const int* __restrict__ srcA,
                                                  const int* __restrict__ dstA,
                                                  int* __restrict__ cursor,
                                                  int* __restrict__ binned, int E, int NB) {
    __shared__ int lc[NB_MAX];
    __shared__ int lbase[NB_MAX];
    int t = threadIdx.x;
    int chunk = (E + gridDim.x - 1) / gridDim.x;
    int e0 = blockIdx.x * chunk;
    int e1 = min(E, e0 + chunk);
    for (int i = t; i < NB; i += 256) lc[i] = 0;
    __syncthreads();
    for (int e = e0 + t; e < e1; e += 256)
        atomicAdd(&lc[dstA[e] >> BK_SHIFT], 1);
    __syncthreads();
    for (int i = t; i < NB; i += 256) {
        int c = lc[i];
        lbase[i] = c ? atomicAdd(&cursor[i], c) : 0;
    }
    __syncthreads();
    for (int i = t; i < NB; i += 256) lc[i] = 0;
    __syncthreads();
    for (int e = e0 + t; e < e1; e += 256) {
        int d = dstA[e];
        int b = d >> BK_SHIFT;
        int r = atomicAdd(&lc[b], 1);
        binned[lbase[b] + r] = srcA[e] | ((d & (BK_NODES - 1)) << 24);
    }
}

// ---------------- per-bucket counting sort -> sorted CSR ----------------
// One block per bucket. col writes land inside the bucket's ~8KB window
// (L2-resident lines), so HBM write traffic ~= E*4B.
__global__ __launch_bounds__(256) void bsort_kernel(const int* __restrict__ binned,
                                                    const int* __restrict__ bbase,
                                                    int* __restrict__ col,
                                                    int* __restrict__ row_start, int N) {
    __shared__ int cnt[BK_NODES];
    __shared__ int base[BK_NODES];
    __shared__ int s[BK_NODES];
    int b = blockIdx.x, t = threadIdx.x;
    int e0 = bbase[b], e1 = bbase[b + 1];
    if (t < BK_NODES) cnt[t] = 0;
    __syncthreads();
    for (int e = e0 + t; e < e1; e += 256)
        atomicAdd(&cnt[(unsigned)binned[e] >> 24], 1);
    __syncthreads();
    int v = (t < BK_NODES) ? cnt[t] : 0;
    if (t < BK_NODES) s[t] = v;
    __syncthreads();
    for (int off = 1; off < BK_NODES; off <<= 1) {
        int x = 0;
        if (t < BK_NODES && t >= off) x = s[t - off];
        __syncthreads();
        if (t < BK_NODES) s[t] += x;
        __syncthreads();
    }
    if (t < BK_NODES) {
        base[t] = e0 + s[t] - v;          // exclusive within bucket
        int node = b * BK_NODES + t;
        if (node < N) row_start[node] = base[t];
        cnt[t] = 0;                        // reuse as cursor
    }
    if (b == gridDim.x - 1 && t == 0) row_start[N] = e1;
    __syncthreads();
    for (int e = e0 + t; e < e1; e += 256) {
        unsigned p = (unsigned)binned[e];
        int dl = p >> 24;
        int pos = base[dl] + atomicAdd(&cnt[dl], 1);
        col[pos] = p & 0xFFFFFF;
    }
}

// ---------------- mean aggregation (16-lane group per node, CSR) ----------------
// FV float4s per row live (16 for F=64, 10 for F=40). L3: OUT holds self-path,
// add and write back in place.
template<int FV, int LDX, bool L3>
__global__ __launch_bounds__(256) void agg_kernel(const float* __restrict__ X,
                                                  const int* __restrict__ rs,
                                                  const int* __restrict__ col,
                                                  float* __restrict__ OUT, int n) {
    int t = threadIdx.x;
    int node = blockIdx.x * 16 + (t >> 4);
    if (node >= n) return;
    int lane = t & 15;
    int s = rs[node], d = rs[node + 1] - s;
    bool act = lane < FV;
    float ax = 0.f, ay = 0.f, az = 0.f, aw = 0.f;
    const float* lp = X + (size_t)lane * 4;
    int j = 0;
    for (; j + 3 < d; j += 4) {
        int c0 = col[s + j], c1 = col[s + j + 1];
        int c2 = col[s + j + 2], c3 = col[s + j + 3];
        if (act) {
            float4 v0 = *(const float4*)(lp + (size_t)c0 * LDX);
            float4 v1 = *(const float4*)(lp + (size_t)c1 * LDX);
            float4 v2 = *(const float4*)(lp + (size_t)c2 * LDX);
            float4 v3 = *(const float4*)(lp + (size_t)c3 * LDX);
            ax += (v0.x + v1.x) + (v2.x + v3.x);
            ay += (v0.y + v1.y) + (v2.y + v3.y);
            az += (v0.z + v1.z) + (v2.z + v3.z);
            aw += (v0.w + v1.w) + (v2.w + v3.w);
        }
    }
    for (; j < d; ++j) {
        int c0 = col[s + j];
        if (act) {
            float4 v0 = *(const float4*)(lp + (size_t)c0 * LDX);
            ax += v0.x; ay += v0.y; az += v0.z; aw += v0.w;
        }
    }
    float w = 1.f / (float)(d > 0 ? d : 1);
    ax *= w; ay *= w; az *= w; aw *= w;
    if (act) {
        float* op = OUT + (size_t)node * LDX + lane * 4;
        if (L3) {
            float4 r = *(const float4*)op;
            ax += r.x; ay += r.y; az += r.z; aw += r.w;
        }
        float4 o; o.x = ax; o.y = ay; o.z = az; o.w = aw;
        *(float4*)op = o;
    }
}

// ---------------- fused linear: OUT = relu(A@Wl^T + b + X@Wr^T) ----------------
__global__ __launch_bounds__(256) void lin12_kernel(const float* __restrict__ X,
                                                    const float* __restrict__ A,
                                                    const float* __restrict__ Wl,
                                                    const float* __restrict__ Wr,
                                                    const float* __restrict__ bias,
                                                    float* __restrict__ OUT) {
    __shared__ float Wls[64][65];
    __shared__ float Wrs[64][65];
    __shared__ float Xs[32][65];
    __shared__ float As[32][65];
    int t = threadIdx.x;
    int rowbase = blockIdx.x * 32;
#pragma unroll
    for (int it = 0; it < 4; ++it) {
        int idx4 = it * 256 + t;          // 1024 float4 = 64x64
        int c = idx4 >> 4, kq = (idx4 & 15) * 4;
        float4 wl = ((const float4*)Wl)[idx4];
        float4 wr = ((const float4*)Wr)[idx4];
        Wls[c][kq] = wl.x; Wls[c][kq + 1] = wl.y; Wls[c][kq + 2] = wl.z; Wls[c][kq + 3] = wl.w;
        Wrs[c][kq] = wr.x; Wrs[c][kq + 1] = wr.y; Wrs[c][kq + 2] = wr.z; Wrs[c][kq + 3] = wr.w;
    }
#pragma unroll
    for (int it = 0; it < 2; ++it) {
        int idx4 = it * 256 + t;          // 512 float4 = 32 rows x 16
        int r = idx4 >> 4, kq = (idx4 & 15) * 4;
        float4 xv = ((const float4*)(X + (size_t)(rowbase + r) * 64))[idx4 & 15];
        float4 av = ((const float4*)(A + (size_t)(rowbase + r) * 64))[idx4 & 15];
        Xs[r][kq] = xv.x; Xs[r][kq + 1] = xv.y; Xs[r][kq + 2] = xv.z; Xs[r][kq + 3] = xv.w;
        As[r][kq] = av.x; As[r][kq + 1] = av.y; As[r][kq + 2] = av.z; As[r][kq + 3] = av.w;
    }
    __syncthreads();
    int rp = t >> 4, cg = t & 15;
    int r0 = rp * 2, r1 = r0 + 1, c0 = cg * 4;
    float4 acc0 = {0, 0, 0, 0}, acc1 = {0, 0, 0, 0};
#pragma unroll
    for (int k = 0; k < 64; ++k) {
        float a0 = As[r0][k], a1 = As[r1][k];
        float x0 = Xs[r0][k], x1 = Xs[r1][k];
        float wl0 = Wls[c0][k], wl1 = Wls[c0 + 1][k], wl2 = Wls[c0 + 2][k], wl3 = Wls[c0 + 3][k];
        float wr0 = Wrs[c0][k], wr1 = Wrs[c0 + 1][k], wr2 = Wrs[c0 + 2][k], wr3 = Wrs[c0 + 3][k];
        acc0.x = fmaf(a0, wl0, fmaf(x0, wr0, acc0.x));
        acc0.y = fmaf(a0, wl1, fmaf(x0, wr1, acc0.y));
        acc0.z = fmaf(a0, wl2, fmaf(x0, wr2, acc0.z));
        acc0.w = fmaf(a0, wl3, fmaf(x0, wr3, acc0.w));
        acc1.x = fmaf(a1, wl0, fmaf(x1, wr0, acc1.x));
        acc1.y = fmaf(a1, wl1, fmaf(x1, wr1, acc1.y));
        acc1.z = fmaf(a1, wl2, fmaf(x1, wr2, acc1.z));
        acc1.w = fmaf(a1, wl3, fmaf(x1, wr3, acc1.w));
    }
    float4 bb = ((const float4*)bias)[cg];
    acc0.x = fmaxf(acc0.x + bb.x, 0.f); acc0.y = fmaxf(acc0.y + bb.y, 0.f);
    acc0.z = fmaxf(acc0.z + bb.z, 0.f); acc0.w = fmaxf(acc0.w + bb.w, 0.f);
    acc1.x = fmaxf(acc1.x + bb.x, 0.f); acc1.y = fmaxf(acc1.y + bb.y, 0.f);
    acc1.z = fmaxf(acc1.z + bb.z, 0.f); acc1.w = fmaxf(acc1.w + bb.w, 0.f);
    ((float4*)(OUT + (size_t)(rowbase + r0) * 64))[cg] = acc0;
    ((float4*)(OUT + (size_t)(rowbase + r1) * 64))[cg] = acc1;
}

// ---------------- layer-3 pre-transform: Z = X@Wl3^T (N,40), R = X@Wr3^T + b3 ----------------
__global__ __launch_bounds__(256) void lin3_kernel(const float* __restrict__ X,
                                                   const float* __restrict__ Wl,
                                                   const float* __restrict__ Wr,
                                                   const float* __restrict__ bias,
                                                   float* __restrict__ Z,
                                                   float* __restrict__ R) {
    __shared__ float Ws[80][65];
    __shared__ float Xs[20][65];
    int t = threadIdx.x;
    int rowbase = blockIdx.x * 20;
#pragma unroll
    for (int it = 0; it < 5; ++it) {
        int idx4 = it * 256 + t;          // 1280 float4 = 80x64
        int c = idx4 >> 4, kq = (idx4 & 15) * 4;
        float4 w = (c < 40) ? ((const float4*)Wl)[idx4] : ((const float4*)Wr)[idx4 - 640];
        Ws[c][kq] = w.x; Ws[c][kq + 1] = w.y; Ws[c][kq + 2] = w.z; Ws[c][kq + 3] = w.w;
    }
#pragma unroll
    for (int it = 0; it < 2; ++it) {
        int idx4 = it * 256 + t;          // 320 float4 = 20 rows x 16
        if (idx4 < 320) {
            int r = idx4 >> 4, kq = (idx4 & 15) * 4;
            float4 xv = ((const float4*)(X + (size_t)(rowbase + r) * 64))[idx4 & 15];
            Xs[r][kq] = xv.x; Xs[r][kq + 1] = xv.y; Xs[r][kq + 2] = xv.z; Xs[r][kq + 3] = xv.w;
        }
    }
    __syncthreads();
    if (t >= 200) return;
    int rp = t / 20, cg = t % 20;
    int r0 = rp * 2, r1 = r0 + 1;
    bool lpath = cg < 10;
    int c0 = (lpath ? cg : cg - 10) * 4;
    int wc = lpath ? c0 : 40 + c0;
    float4 acc0 = {0, 0, 0, 0}, acc1 = {0, 0, 0, 0};
#pragma unroll
    for (int k = 0; k < 64; ++k) {
        float x0 = Xs[r0][k], x1 = Xs[r1][k];
        float w0 = Ws[wc][k], w1 = Ws[wc + 1][k], w2 = Ws[wc + 2][k], w3 = Ws[wc + 3][k];
        acc0.x = fmaf(x0, w0, acc0.x); acc0.y = fmaf(x0, w1, acc0.y);
        acc0.z = fmaf(x0, w2, acc0.z); acc0.w = fmaf(x0, w3, acc0.w);
        acc1.x = fmaf(x1, w0, acc1.x); acc1.y = fmaf(x1, w1, acc1.y);
        acc1.z = fmaf(x1, w2, acc1.z); acc1.w = fmaf(x1, w3, acc1.w);
    }
    if (!lpath) {
        float4 bb = ((const float4*)bias)[c0 >> 2];
        acc0.x += bb.x; acc0.y += bb.y; acc0.z += bb.z; acc0.w += bb.w;
        acc1.x += bb.x; acc1.y += bb.y; acc1.z += bb.z; acc1.w += bb.w;
    }
    float* dp = lpath ? Z : R;
    ((float4*)(dp + (size_t)(rowbase + r0) * 40))[c0 >> 2] = acc0;
    ((float4*)(dp + (size_t)(rowbase + r1) * 40))[c0 >> 2] = acc1;
}

// ---------------- log_softmax in place, one wave per node ----------------
__global__ __launch_bounds__(256) void lsm_kernel(float* __restrict__ out, int n) {
    int t = threadIdx.x;
    int node = blockIdx.x * 4 + (t >> 6);
    if (node >= n) return;
    int lane = t & 63;
    float v = (lane < 40) ? out[(size_t)node * 40 + lane] : -3.4e38f;
    float m = v;
#pragma unroll
    for (int off = 32; off > 0; off >>= 1) m = fmaxf(m, __shfl_xor(m, off));
    float e = (lane < 40) ? expf(v - m) : 0.f;
    float ssum = e;
#pragma unroll
    for (int off = 32; off > 0; off >>= 1) ssum += __shfl_xor(ssum, off);
    if (lane < 40) out[(size_t)node * 40 + lane] = v - m - logf(ssum);
}

// ---------------- launch ----------------
extern "C" void kernel_launch(void* const* d_in, const int* in_sizes, int n_in,
                              void* d_out, int out_size, void* d_ws, size_t ws_size,
                              hipStream_t stream) {
    const float* x   = (const float*)d_in[0];
    const int*   ei  = (const int*)d_in[1];
    const float* Wl1 = (const float*)d_in[2];
    const float* Wr1 = (const float*)d_in[3];
    const float* b1  = (const float*)d_in[4];
    const float* Wl2 = (const float*)d_in[5];
    const float* Wr2 = (const float*)d_in[6];
    const float* b2  = (const float*)d_in[7];
    const float* Wl3 = (const float*)d_in[8];
    const float* Wr3 = (const float*)d_in[9];
    const float* b3  = (const float*)d_in[10];
    float* out = (float*)d_out;

    const int N = in_sizes[0] / 64;
    const int E = in_sizes[1] / 2;
    const int NB = (N + BK_NODES - 1) / BK_NODES;   // 782 for N=100000
    const int* srcA = ei;
    const int* dstA = ei + E;

    char* ws = (char*)d_ws;
    size_t off = 0;
    auto alloc = [&](size_t bytes) {
        off = (off + 255) & ~(size_t)255;
        char* p = ws + off;
        off += bytes;
        return p;
    };
    int*   bcount    = (int*)alloc((size_t)(NB_MAX + 1) * 4);
    int*   bbase     = (int*)alloc((size_t)(NB_MAX + 1) * 4);
    int*   cursor    = (int*)alloc((size_t)NB_MAX * 4);
    int*   binned    = (int*)alloc((size_t)E * 4);
    int*   col       = (int*)alloc((size_t)E * 4);
    int*   row_start = (int*)alloc((size_t)(N + 1) * 4);
    float* AGG       = (float*)alloc((size_t)N * 64 * 4);
    float* Hb        = (float*)alloc((size_t)N * 64 * 4);

    // build sorted CSR via dst-buckets
    hipMemsetAsync(bcount, 0, (size_t)(NB + 1) * 4, stream);
    bcount_kernel<<<256, 256, 0, stream>>>(dstA, bcount, E, NB);
    bscan_kernel<<<1, 1024, 0, stream>>>(bcount, bbase, cursor, NB, E);
    bin_kernel<<<128, 256, 0, stream>>>(srcA, dstA, cursor, binned, E, NB);
    bsort_kernel<<<NB, 256, 0, stream>>>(binned, bbase, col, row_start, N);

    // layer 1: h1 = relu(mean(x)@Wl1^T + b1 + x@Wr1^T)
    agg_kernel<16, 64, false><<<(N + 15) / 16, 256, 0, stream>>>(x, row_start, col, AGG, N);
    lin12_kernel<<<N / 32, 256, 0, stream>>>(x, AGG, Wl1, Wr1, b1, Hb);

    // layer 2 (in-place on Hb)
    agg_kernel<16, 64, false><<<(N + 15) / 16, 256, 0, stream>>>(Hb, row_start, col, AGG, N);
    lin12_kernel<<<N / 32, 256, 0, stream>>>(Hb, AGG, Wl2, Wr2, b2, Hb);

    // layer 3: pre-transform (agg is linear): Z = h2@Wl3^T (N,40) in AGG, R = h2@Wr3^T+b3 in d_out
    lin3_kernel<<<N / 20, 256, 0, stream>>>(Hb, Wl3, Wr3, b3, AGG, out);
    agg_kernel<10, 40, true><<<(N + 15) / 16, 256, 0, stream>>>(AGG, row_start, col, out, N);

    // log_softmax in place
    lsm_kernel<<<(N + 3) / 4, 256, 0, stream>>>(out, N);
}

// Round 5
// 312.884 us; speedup vs baseline: 6.7453x; 1.6602x over previous
//
#include <hip/hip_runtime.h>
#include <hip/hip_bf16.h>
#include <math.h>

// GraphSAGE 3-layer, mean aggr. Round 4 (resubmit after broker timeout):
// bf16 activations + MFMA linears.
// Build (unchanged, proven): bucket count -> scan -> bin -> per-bucket sort => CSR.
// xconv: x fp32 -> bf16. wconv: weights fp32 -> bf16 concat layouts.
// agg64: CSR mean-gather on bf16 rows (128B), fp32 accum, bf16 out.
// linmfma12: out = relu([A|X] @ [Wl|Wr]^T + b), K=128, mfma 16x16x32 bf16.
// linmfma3: Z = h2@Wl3^T (bf16), R = h2@Wr3^T + b3 (fp32 -> d_out).
// agg40lsm: mean(Z) + R, then log_softmax fused (16-lane shuffle reduce).

#define BK_SHIFT 7
#define BK_NODES 128
#define NB_MAX   1024

typedef __attribute__((ext_vector_type(8))) short short8;
typedef __attribute__((ext_vector_type(4))) float f32x4;

__device__ inline float blo(unsigned v) { union { unsigned u; float f; } c; c.u = v << 16; return c.f; }
__device__ inline float bhi(unsigned v) { union { unsigned u; float f; } c; c.u = v & 0xFFFF0000u; return c.f; }
__device__ inline unsigned short f2bf(float f) {
    union { float f; unsigned u; } c; c.f = f;
    unsigned r = (c.u + 0x7FFFu + ((c.u >> 16) & 1u)) >> 16;
    return (unsigned short)r;
}

// ---------------- bucket count ----------------
__global__ __launch_bounds__(256) void bcount_kernel(const int* __restrict__ dstA,
                                                     int* __restrict__ bcount, int E, int NB) {
    __shared__ int lc[NB_MAX];
    int t = threadIdx.x;
    for (int i = t; i < NB; i += 256) lc[i] = 0;
    __syncthreads();
    int step = gridDim.x * 256;
    for (int e = blockIdx.x * 256 + t; e < E; e += step)
        atomicAdd(&lc[dstA[e] >> BK_SHIFT], 1);
    __syncthreads();
    for (int i = t; i < NB; i += 256)
        if (lc[i]) atomicAdd(&bcount[i], lc[i]);
}

// ---------------- scan bucket counts ----------------
__global__ __launch_bounds__(1024) void bscan_kernel(const int* __restrict__ bcount,
                                                     int* __restrict__ bbase,
                                                     int* __restrict__ cursor, int NB, int E) {
    __shared__ int s[1024];
    int t = threadIdx.x;
    int v = (t < NB) ? bcount[t] : 0;
    s[t] = v;
    __syncthreads();
    for (int off = 1; off < 1024; off <<= 1) {
        int x = 0;
        if (t >= off) x = s[t - off];
        __syncthreads();
        s[t] += x;
        __syncthreads();
    }
    if (t < NB) {
        int ex = s[t] - v;
        bbase[t] = ex;
        cursor[t] = ex;
    }
    if (t == 0) bbase[NB] = E;
}

// ---------------- bin edges (src | dstLocal<<24) ----------------
__global__ __launch_bounds__(256) void bin_kernel(const int* __restrict__ srcA,
                                                  const int* __restrict__ dstA,
                                                  int* __restrict__ cursor,
                                                  int* __restrict__ binned, int E, int NB) {
    __shared__ int lc[NB_MAX];
    __shared__ int lbase[NB_MAX];
    int t = threadIdx.x;
    int chunk = (E + gridDim.x - 1) / gridDim.x;
    int e0 = blockIdx.x * chunk;
    int e1 = min(E, e0 + chunk);
    for (int i = t; i < NB; i += 256) lc[i] = 0;
    __syncthreads();
    for (int e = e0 + t; e < e1; e += 256)
        atomicAdd(&lc[dstA[e] >> BK_SHIFT], 1);
    __syncthreads();
    for (int i = t; i < NB; i += 256) {
        int c = lc[i];
        lbase[i] = c ? atomicAdd(&cursor[i], c) : 0;
    }
    __syncthreads();
    for (int i = t; i < NB; i += 256) lc[i] = 0;
    __syncthreads();
    for (int e = e0 + t; e < e1; e += 256) {
        int d = dstA[e];
        int b = d >> BK_SHIFT;
        int r = atomicAdd(&lc[b], 1);
        binned[lbase[b] + r] = srcA[e] | ((d & (BK_NODES - 1)) << 24);
    }
}

// ---------------- per-bucket counting sort -> sorted CSR ----------------
__global__ __launch_bounds__(256) void bsort_kernel(const int* __restrict__ binned,
                                                    const int* __restrict__ bbase,
                                                    int* __restrict__ col,
                                                    int* __restrict__ row_start, int N) {
    __shared__ int cnt[BK_NODES];
    __shared__ int base[BK_NODES];
    __shared__ int s[BK_NODES];
    int b = blockIdx.x, t = threadIdx.x;
    int e0 = bbase[b], e1 = bbase[b + 1];
    if (t < BK_NODES) cnt[t] = 0;
    __syncthreads();
    for (int e = e0 + t; e < e1; e += 256)
        atomicAdd(&cnt[(unsigned)binned[e] >> 24], 1);
    __syncthreads();
    int v = (t < BK_NODES) ? cnt[t] : 0;
    if (t < BK_NODES) s[t] = v;
    __syncthreads();
    for (int off = 1; off < BK_NODES; off <<= 1) {
        int x = 0;
        if (t < BK_NODES && t >= off) x = s[t - off];
        __syncthreads();
        if (t < BK_NODES) s[t] += x;
        __syncthreads();
    }
    if (t < BK_NODES) {
        base[t] = e0 + s[t] - v;
        int node = b * BK_NODES + t;
        if (node < N) row_start[node] = base[t];
        cnt[t] = 0;
    }
    if (b == gridDim.x - 1 && t == 0) row_start[N] = e1;
    __syncthreads();
    for (int e = e0 + t; e < e1; e += 256) {
        unsigned p = (unsigned)binned[e];
        int dl = p >> 24;
        int pos = base[dl] + atomicAdd(&cnt[dl], 1);
        col[pos] = p & 0xFFFFFF;
    }
}

// ---------------- x fp32 -> bf16 ----------------
__global__ __launch_bounds__(256) void xconv_kernel(const float* __restrict__ x,
                                                    unsigned short* __restrict__ Xb, int n8) {
    int i = blockIdx.x * 256 + threadIdx.x;
    if (i >= n8) return;
    const float* p = x + (size_t)i * 8;
    float4 a = *(const float4*)p;
    float4 b = *(const float4*)(p + 4);
    uint4 o;
    o.x = f2bf(a.x) | ((unsigned)f2bf(a.y) << 16);
    o.y = f2bf(a.z) | ((unsigned)f2bf(a.w) << 16);
    o.z = f2bf(b.x) | ((unsigned)f2bf(b.y) << 16);
    o.w = f2bf(b.z) | ((unsigned)f2bf(b.w) << 16);
    *(uint4*)(Xb + (size_t)i * 8) = o;
}

// ---------------- weights fp32 -> bf16 concat layouts ----------------
// Wb1/Wb2: [64][128] = [Wl | Wr].  Wb3: [96][64] = rows 0..39 Wl3, 48..87 Wr3, else 0.
__global__ __launch_bounds__(256) void wconv_kernel(const float* __restrict__ Wl1, const float* __restrict__ Wr1,
                                                    const float* __restrict__ Wl2, const float* __restrict__ Wr2,
                                                    const float* __restrict__ Wl3, const float* __restrict__ Wr3,
                                                    unsigned short* __restrict__ Wb1,
                                                    unsigned short* __restrict__ Wb2,
                                                    unsigned short* __restrict__ Wb3) {
    int i = blockIdx.x * 256 + threadIdx.x;
    if (i < 8192) {
        int c = i >> 7, k = i & 127;
        float v = (k < 64) ? Wl1[c * 64 + k] : Wr1[c * 64 + k - 64];
        Wb1[i] = f2bf(v);
    } else if (i < 16384) {
        int j = i - 8192;
        int c = j >> 7, k = j & 127;
        float v = (k < 64) ? Wl2[c * 64 + k] : Wr2[c * 64 + k - 64];
        Wb2[j] = f2bf(v);
    } else if (i < 22528) {
        int j = i - 16384;
        int c = j >> 6, k = j & 63;
        float v = 0.f;
        if (c < 40) v = Wl3[c * 64 + k];
        else if (c >= 48 && c < 88) v = Wr3[(c - 48) * 64 + k];
        Wb3[j] = f2bf(v);
    }
}

// ---------------- mean aggregation, 64 bf16 dims (16-lane group/node) ----------------
__global__ __launch_bounds__(256) void agg64_kernel(const unsigned short* __restrict__ X,
                                                    const int* __restrict__ rs,
                                                    const int* __restrict__ col,
                                                    unsigned short* __restrict__ OUT, int n) {
    int t = threadIdx.x;
    int node = blockIdx.x * 16 + (t >> 4);
    if (node >= n) return;
    int lane = t & 15;
    int s = rs[node], d = rs[node + 1] - s;
    const unsigned short* lp = X + lane * 4;
    float ax = 0.f, ay = 0.f, az = 0.f, aw = 0.f;
    int j = 0;
    for (; j + 3 < d; j += 4) {
        int c0 = col[s + j], c1 = col[s + j + 1];
        int c2 = col[s + j + 2], c3 = col[s + j + 3];
        uint2 q0 = *(const uint2*)(lp + (size_t)c0 * 64);
        uint2 q1 = *(const uint2*)(lp + (size_t)c1 * 64);
        uint2 q2 = *(const uint2*)(lp + (size_t)c2 * 64);
        uint2 q3 = *(const uint2*)(lp + (size_t)c3 * 64);
        ax += (blo(q0.x) + blo(q1.x)) + (blo(q2.x) + blo(q3.x));
        ay += (bhi(q0.x) + bhi(q1.x)) + (bhi(q2.x) + bhi(q3.x));
        az += (blo(q0.y) + blo(q1.y)) + (blo(q2.y) + blo(q3.y));
        aw += (bhi(q0.y) + bhi(q1.y)) + (bhi(q2.y) + bhi(q3.y));
    }
    for (; j < d; ++j) {
        int c0 = col[s + j];
        uint2 q0 = *(const uint2*)(lp + (size_t)c0 * 64);
        ax += blo(q0.x); ay += bhi(q0.x); az += blo(q0.y); aw += bhi(q0.y);
    }
    float w = 1.f / (float)(d > 0 ? d : 1);
    ax *= w; ay *= w; az *= w; aw *= w;
    uint2 o;
    o.x = f2bf(ax) | ((unsigned)f2bf(ay) << 16);
    o.y = f2bf(az) | ((unsigned)f2bf(aw) << 16);
    *(uint2*)(OUT + (size_t)node * 64 + lane * 4) = o;
}

// ---------------- MFMA linear 1/2: OUT = relu([A|X]@Wb^T + b), K=128 ----------------
__global__ __launch_bounds__(256) void linmfma12_kernel(const unsigned short* __restrict__ A,
                                                        const unsigned short* __restrict__ X,
                                                        const unsigned short* __restrict__ Wb,
                                                        const float* __restrict__ bias,
                                                        unsigned short* __restrict__ OUT,
                                                        int N) {
    __shared__ unsigned short Ys[64][136];
    __shared__ unsigned short Ws[64][136];
    int t = threadIdx.x;
    int rowbase = blockIdx.x * 64;
#pragma unroll
    for (int it = 0; it < 4; ++it) {
        int idx = it * 256 + t;
        int row = idx >> 4, c = idx & 15;
        int grow = rowbase + row;
        if (grow >= N) grow = N - 1;
        const unsigned short* src = (c < 8) ? (A + (size_t)grow * 64 + c * 8)
                                            : (X + (size_t)grow * 64 + (c - 8) * 8);
        *(short8*)&Ys[row][c * 8] = *(const short8*)src;
        *(short8*)&Ws[row][c * 8] = *(const short8*)(Wb + (size_t)row * 128 + c * 8);
    }
    __syncthreads();
    int l = t & 63, w = t >> 6;
    int lrow = l & 15, lk = l >> 4;
    f32x4 acc0 = {0.f, 0.f, 0.f, 0.f};
    f32x4 acc1 = acc0, acc2 = acc0, acc3 = acc0;
#pragma unroll
    for (int kk = 0; kk < 4; ++kk) {
        int ko = kk * 32 + lk * 8;
        short8 a  = *(const short8*)&Ys[16 * w + lrow][ko];
        short8 b0 = *(const short8*)&Ws[lrow][ko];
        short8 b1 = *(const short8*)&Ws[16 + lrow][ko];
        short8 b2 = *(const short8*)&Ws[32 + lrow][ko];
        short8 b3 = *(const short8*)&Ws[48 + lrow][ko];
        acc0 = __builtin_amdgcn_mfma_f32_16x16x32_bf16(a, b0, acc0, 0, 0, 0);
        acc1 = __builtin_amdgcn_mfma_f32_16x16x32_bf16(a, b1, acc1, 0, 0, 0);
        acc2 = __builtin_amdgcn_mfma_f32_16x16x32_bf16(a, b2, acc2, 0, 0, 0);
        acc3 = __builtin_amdgcn_mfma_f32_16x16x32_bf16(a, b3, acc3, 0, 0, 0);
    }
#define EPI12(nt, accv)                                                   \
    {                                                                     \
        int colc = 16 * (nt) + lrow;                                      \
        float bv = bias[colc];                                            \
        _Pragma("unroll") for (int i = 0; i < 4; ++i) {                   \
            int grow = rowbase + 16 * w + lk * 4 + i;                     \
            if (grow < N) {                                               \
                float v = fmaxf(accv[i] + bv, 0.f);                       \
                OUT[(size_t)grow * 64 + colc] = f2bf(v);                  \
            }                                                             \
        }                                                                 \
    }
    EPI12(0, acc0) EPI12(1, acc1) EPI12(2, acc2) EPI12(3, acc3)
#undef EPI12
}

// ---------------- MFMA linear 3: Z = h2@Wl3^T (bf16), R = h2@Wr3^T + b3 (fp32) ----------------
// Wb3 layout [96][64]: cols 0..39 -> Z, 48..87 -> R, rest dead.
__global__ __launch_bounds__(256) void linmfma3_kernel(const unsigned short* __restrict__ H,
                                                       const unsigned short* __restrict__ Wb3,
                                                       const float* __restrict__ b3,
                                                       unsigned short* __restrict__ Z,
                                                       float* __restrict__ R,
                                                       int N) {
    __shared__ unsigned short Ys[64][72];
    __shared__ unsigned short Ws[96][72];
    int t = threadIdx.x;
    int rowbase = blockIdx.x * 64;
#pragma unroll
    for (int it = 0; it < 2; ++it) {
        int idx = it * 256 + t;             // 512 chunks = 64 rows x 8
        int row = idx >> 3, c = idx & 7;
        int grow = rowbase + row;
        if (grow >= N) grow = N - 1;
        *(short8*)&Ys[row][c * 8] = *(const short8*)(H + (size_t)grow * 64 + c * 8);
    }
#pragma unroll
    for (int it = 0; it < 3; ++it) {
        int idx = it * 256 + t;             // 768 chunks = 96 rows x 8
        int row = idx >> 3, c = idx & 7;
        *(short8*)&Ws[row][c * 8] = *(const short8*)(Wb3 + (size_t)row * 64 + c * 8);
    }
    __syncthreads();
    int l = t & 63, w = t >> 6;
    int lrow = l & 15, lk = l >> 4;
    f32x4 acc0 = {0.f, 0.f, 0.f, 0.f};
    f32x4 acc1 = acc0, acc2 = acc0, acc3 = acc0, acc4 = acc0, acc5 = acc0;
#pragma unroll
    for (int kk = 0; kk < 2; ++kk) {
        int ko = kk * 32 + lk * 8;
        short8 a  = *(const short8*)&Ys[16 * w + lrow][ko];
        short8 b0 = *(const short8*)&Ws[lrow][ko];
        short8 b1 = *(const short8*)&Ws[16 + lrow][ko];
        short8 b2 = *(const short8*)&Ws[32 + lrow][ko];
        short8 b3f = *(const short8*)&Ws[48 + lrow][ko];
        short8 b4 = *(const short8*)&Ws[64 + lrow][ko];
        short8 b5 = *(const short8*)&Ws[80 + lrow][ko];
        acc0 = __builtin_amdgcn_mfma_f32_16x16x32_bf16(a, b0, acc0, 0, 0, 0);
        acc1 = __builtin_amdgcn_mfma_f32_16x16x32_bf16(a, b1, acc1, 0, 0, 0);
        acc2 = __builtin_amdgcn_mfma_f32_16x16x32_bf16(a, b2, acc2, 0, 0, 0);
        acc3 = __builtin_amdgcn_mfma_f32_16x16x32_bf16(a, b3f, acc3, 0, 0, 0);
        acc4 = __builtin_amdgcn_mfma_f32_16x16x32_bf16(a, b4, acc4, 0, 0, 0);
        acc5 = __builtin_amdgcn_mfma_f32_16x16x32_bf16(a, b5, acc5, 0, 0, 0);
    }
#define EPI3(nt, accv)                                                     \
    {                                                                      \
        int colc = 16 * (nt) + lrow;                                       \
        _Pragma("unroll") for (int i = 0; i < 4; ++i) {                    \
            int grow = rowbase + 16 * w + lk * 4 + i;                      \
            if (grow < N) {                                                \
                float v = accv[i];                                         \
                if (colc < 40) {                                           \
                    Z[(size_t)grow * 40 + colc] = f2bf(v);                 \
                } else if (colc >= 48 && colc < 88) {                      \
                    R[(size_t)grow * 40 + (colc - 48)] = v + b3[colc - 48];\
                }                                                          \
            }                                                              \
        }                                                                  \
    }
    EPI3(0, acc0) EPI3(1, acc1) EPI3(2, acc2) EPI3(3, acc3) EPI3(4, acc4) EPI3(5, acc5)
#undef EPI3
}

// ---------------- agg(40 bf16) + self-path add + fused log_softmax ----------------
__global__ __launch_bounds__(256) void agg40lsm_kernel(const unsigned short* __restrict__ Z,
                                                       const int* __restrict__ rs,
                                                       const int* __restrict__ col,
                                                       float* __restrict__ out, int n) {
    int t = threadIdx.x;
    int node = blockIdx.x * 16 + (t >> 4);
    if (node >= n) return;
    int lane = t & 15;
    bool act = lane < 10;
    int s = rs[node], d = rs[node + 1] - s;
    const unsigned short* lp = Z + lane * 4;
    float ax = 0.f, ay = 0.f, az = 0.f, aw = 0.f;
    int j = 0;
    for (; j + 3 < d; j += 4) {
        int c0 = col[s + j], c1 = col[s + j + 1];
        int c2 = col[s + j + 2], c3 = col[s + j + 3];
        if (act) {
            uint2 q0 = *(const uint2*)(lp + (size_t)c0 * 40);
            uint2 q1 = *(const uint2*)(lp + (size_t)c1 * 40);
            uint2 q2 = *(const uint2*)(lp + (size_t)c2 * 40);
            uint2 q3 = *(const uint2*)(lp + (size_t)c3 * 40);
            ax += (blo(q0.x) + blo(q1.x)) + (blo(q2.x) + blo(q3.x));
            ay += (bhi(q0.x) + bhi(q1.x)) + (bhi(q2.x) + bhi(q3.x));
            az += (blo(q0.y) + blo(q1.y)) + (blo(q2.y) + blo(q3.y));
            aw += (bhi(q0.y) + bhi(q1.y)) + (bhi(q2.y) + bhi(q3.y));
        }
    }
    for (; j < d; ++j) {
        int c0 = col[s + j];
        if (act) {
            uint2 q0 = *(const uint2*)(lp + (size_t)c0 * 40);
            ax += blo(q0.x); ay += bhi(q0.x); az += blo(q0.y); aw += bhi(q0.y);
        }
    }
    float w = 1.f / (float)(d > 0 ? d : 1);
    if (act) {
        float4 rv = *(const float4*)(out + (size_t)node * 40 + lane * 4);
        ax = ax * w + rv.x; ay = ay * w + rv.y;
        az = az * w + rv.z; aw = aw * w + rv.w;
    }
    // fused log_softmax over the 40 values spread across 10 lanes x 4
    float mx = act ? fmaxf(fmaxf(ax, ay), fmaxf(az, aw)) : -3.4e38f;
#pragma unroll
    for (int off = 1; off < 16; off <<= 1) mx = fmaxf(mx, __shfl_xor(mx, off, 16));
    float ssum = act ? (expf(ax - mx) + expf(ay - mx) + expf(az - mx) + expf(aw - mx)) : 0.f;
#pragma unroll
    for (int off = 1; off < 16; off <<= 1) ssum += __shfl_xor(ssum, off, 16);
    float lg = mx + logf(ssum);
    if (act) {
        float4 o;
        o.x = ax - lg; o.y = ay - lg; o.z = az - lg; o.w = aw - lg;
        *(float4*)(out + (size_t)node * 40 + lane * 4) = o;
    }
}

// ---------------- launch ----------------
extern "C" void kernel_launch(void* const* d_in, const int* in_sizes, int n_in,
                              void* d_out, int out_size, void* d_ws, size_t ws_size,
                              hipStream_t stream) {
    const float* x   = (const float*)d_in[0];
    const int*   ei  = (const int*)d_in[1];
    const float* Wl1 = (const float*)d_in[2];
    const float* Wr1 = (const float*)d_in[3];
    const float* b1  = (const float*)d_in[4];
    const float* Wl2 = (const float*)d_in[5];
    const float* Wr2 = (const float*)d_in[6];
    const float* b2  = (const float*)d_in[7];
    const float* Wl3 = (const float*)d_in[8];
    const float* Wr3 = (const float*)d_in[9];
    const float* b3  = (const float*)d_in[10];
    float* out = (float*)d_out;

    const int N = in_sizes[0] / 64;
    const int E = in_sizes[1] / 2;
    const int NB = (N + BK_NODES - 1) / BK_NODES;
    const int* srcA = ei;
    const int* dstA = ei + E;

    char* ws = (char*)d_ws;
    size_t off = 0;
    auto alloc = [&](size_t bytes) {
        off = (off + 255) & ~(size_t)255;
        char* p = ws + off;
        off += bytes;
        return p;
    };
    int* bcount    = (int*)alloc((size_t)(NB_MAX + 1) * 4);
    int* bbase     = (int*)alloc((size_t)(NB_MAX + 1) * 4);
    int* cursor    = (int*)alloc((size_t)NB_MAX * 4);
    int* binned    = (int*)alloc((size_t)E * 4);
    int* col       = (int*)alloc((size_t)E * 4);
    int* row_start = (int*)alloc((size_t)(N + 1) * 4);
    unsigned short* Xb  = (unsigned short*)alloc((size_t)N * 64 * 2);
    unsigned short* AGG = (unsigned short*)alloc((size_t)N * 64 * 2);
    unsigned short* Hb  = (unsigned short*)alloc((size_t)N * 64 * 2);
    unsigned short* Zb  = (unsigned short*)alloc((size_t)N * 40 * 2);
    unsigned short* Wb1 = (unsigned short*)alloc(8192 * 2);
    unsigned short* Wb2 = (unsigned short*)alloc(8192 * 2);
    unsigned short* Wb3 = (unsigned short*)alloc(6144 * 2);

    // build sorted CSR via dst-buckets
    hipMemsetAsync(bcount, 0, (size_t)(NB + 1) * 4, stream);
    bcount_kernel<<<256, 256, 0, stream>>>(dstA, bcount, E, NB);
    bscan_kernel<<<1, 1024, 0, stream>>>(bcount, bbase, cursor, NB, E);
    bin_kernel<<<128, 256, 0, stream>>>(srcA, dstA, cursor, binned, E, NB);
    bsort_kernel<<<NB, 256, 0, stream>>>(binned, bbase, col, row_start, N);

    // dtype conversions
    xconv_kernel<<<(N * 64 / 8 + 255) / 256, 256, 0, stream>>>(x, Xb, N * 64 / 8);
    wconv_kernel<<<88, 256, 0, stream>>>(Wl1, Wr1, Wl2, Wr2, Wl3, Wr3, Wb1, Wb2, Wb3);

    int gridM = (N + 63) / 64;

    // layer 1
    agg64_kernel<<<(N + 15) / 16, 256, 0, stream>>>(Xb, row_start, col, AGG, N);
    linmfma12_kernel<<<gridM, 256, 0, stream>>>(AGG, Xb, Wb1, b1, Hb, N);

    // layer 2 (in-place on Hb: block stages its rows before writing them)
    agg64_kernel<<<(N + 15) / 16, 256, 0, stream>>>(Hb, row_start, col, AGG, N);
    linmfma12_kernel<<<gridM, 256, 0, stream>>>(AGG, Hb, Wb2, b2, Hb, N);

    // layer 3: pre-transform (agg is linear), then agg(40) + self + log_softmax
    linmfma3_kernel<<<gridM, 256, 0, stream>>>(Hb, Wb3, b3, Zb, out, N);
    agg40lsm_kernel<<<(N + 15) / 16, 256, 0, stream>>>(Zb, row_start, col, out, N);
}